// Round 1
// baseline (491.574 us; speedup 1.0000x reference)
//
#include <hip/hip_runtime.h>
#include <math.h>

// NeuralstackOnly: T-step scan, one block per batch row, one thread per D column.
// B=128, T=256, D=256, N_STACK=32.

#define NSTK 32
#define DDIM 256
#define ZO 1e-6f
#define EPSC 1e-8f
#define PEPS 1e-12f

__launch_bounds__(256, 1)
__global__ void neuralstack_kernel(const float* __restrict__ x,
                                   const float* __restrict__ should_pop,
                                   const float* __restrict__ sharpen_ptr,
                                   const float* __restrict__ latch_enable,
                                   const float* __restrict__ latch_init,
                                   float* __restrict__ out,
                                   int T) {
    const int b = blockIdx.x;
    const int tid = threadIdx.x;          // = d column, 0..255
    const int wave = tid >> 6;            // 0..3
    const int lane = tid & 63;

    // double-buffered cross-wave reduction scratch: [buf][wave*4 + k]
    __shared__ float red[2][16];

    const float sp_d = should_pop[tid];
    const float le_d = latch_enable[tid];
    const float sharpen = sharpen_ptr[0];
    float latch = latch_init[(size_t)b * DDIM + tid];

    // ---- precompute parameter norms (constant over t) ----
    float a0 = sp_d * sp_d;
    float a1 = le_d * le_d;
#pragma unroll
    for (int off = 32; off >= 1; off >>= 1) {
        a0 += __shfl_xor(a0, off, 64);
        a1 += __shfl_xor(a1, off, 64);
    }
    if (lane == 0) { red[0][wave * 4 + 0] = a0; red[0][wave * 4 + 1] = a1; }
    __syncthreads();
    const float ssp = red[0][0] + red[0][4] + red[0][8] + red[0][12];
    const float sle = red[0][1] + red[0][5] + red[0][9] + red[0][13];
    const float an_sp = fmaxf(sqrtf(ssp), EPSC);
    const float an_le = fmaxf(sqrtf(sle), EPSC);
    __syncthreads();  // protect red[0] before t=0 writes it

    // ---- per-thread replicated state (all in VGPRs via full unroll) ----
    float st[NSTK];   // stack column for this d
    float ptr[NSTK];  // pointer, replicated across all threads of the block
#pragma unroll
    for (int n = 0; n < NSTK; n++) {
        st[n] = ZO;
        ptr[n] = (n == 0) ? 1.0f : ZO;
    }

    const float* xb = x + (size_t)b * T * DDIM + tid;
    float* ob = out + (size_t)b * T * DDIM + tid;

    const bool sharp5 = (sharpen == 5.0f);

    float inp = xb[0];
    for (int t = 0; t < T; t++) {
        // software-prefetch next timestep's input
        const int tn = (t + 1 < T) ? (t + 1) : (T - 1);
        const float inp_next = xb[(size_t)tn * DDIM];

        // ---- block reductions: sp·latch, latch², le·inp, inp² ----
        float r0 = sp_d * latch;
        float r1 = latch * latch;
        float r2 = le_d * inp;
        float r3 = inp * inp;
#pragma unroll
        for (int off = 32; off >= 1; off >>= 1) {
            r0 += __shfl_xor(r0, off, 64);
            r1 += __shfl_xor(r1, off, 64);
            r2 += __shfl_xor(r2, off, 64);
            r3 += __shfl_xor(r3, off, 64);
        }
        const int buf = t & 1;
        if (lane == 0) {
            red[buf][wave * 4 + 0] = r0;
            red[buf][wave * 4 + 1] = r1;
            red[buf][wave * 4 + 2] = r2;
            red[buf][wave * 4 + 3] = r3;
        }
        __syncthreads();
        const float s0 = red[buf][0] + red[buf][4] + red[buf][8] + red[buf][12];
        const float s1 = red[buf][1] + red[buf][5] + red[buf][9] + red[buf][13];
        const float s2 = red[buf][2] + red[buf][6] + red[buf][10] + red[buf][14];
        const float s3 = red[buf][3] + red[buf][7] + red[buf][11] + red[buf][15];

        // ---- gates ----
        const float c_pop = s0 / (an_sp * fmaxf(sqrtf(s1), EPSC));
        const float pop = (c_pop > 0.f) ? c_pop : expm1f(c_pop);
        const float push = 1.0f - pop;
        const float c_g = s2 / (an_le * fmaxf(sqrtf(s3), EPSC));
        const float g = (c_g > 0.f) ? c_g : expm1f(c_g);

        // ---- pointer update + sharpen (redundant on every thread) ----
        float q[NSTK];
#pragma unroll
        for (int n = 0; n < NSTK; n++) {
            const float pp = ptr[(n + NSTK - 1) & (NSTK - 1)];  // roll +1
            const float pn = ptr[(n + 1) & (NSTK - 1)];         // roll -1
            const float np_ = push * pp + pop * pn;
            q[n] = fmaxf(np_, PEPS);  // == max(relu(np_), PEPS)
        }
        if (sharp5) {
#pragma unroll
            for (int n = 0; n < NSTK; n++) {
                const float v = q[n];
                const float v2 = v * v;
                q[n] = v2 * v2 * v;
            }
        } else {
#pragma unroll
            for (int n = 0; n < NSTK; n++) {
                q[n] = exp2f(sharpen * log2f(q[n]));
            }
        }
        float qa = 0.f, qb = 0.f, qc = 0.f, qd = 0.f;
#pragma unroll
        for (int n = 0; n < NSTK; n += 4) {
            qa += q[n]; qb += q[n + 1]; qc += q[n + 2]; qd += q[n + 3];
        }
        const float qs = (qa + qb) + (qc + qd);
        const float inv = 1.0f / fmaxf(qs, EPSC);

        // ---- stack update + readout dot ----
        float sacc = 0.f;
#pragma unroll
        for (int n = 0; n < NSTK; n++) {
            const float pp = ptr[(n + NSTK - 1) & (NSTK - 1)];
            const float pc = ptr[n];
            const float stp = st[n] + pp * (inp - st[n]);  // push branch
            const float sto = st[n] + pc * (ZO - st[n]);   // pop branch
            const float ns = push * stp + pop * sto;
            st[n] = ns;
            sacc += ns * (q[n] * inv);
        }
#pragma unroll
        for (int n = 0; n < NSTK; n++) ptr[n] = q[n] * inv;  // carry = sharpened p

        ob[(size_t)t * DDIM] = pop * sacc;

        // ---- latch update (uses pre-update latch; g from inp) ----
        latch = latch + g * (inp - latch);

        inp = inp_next;
    }
}

extern "C" void kernel_launch(void* const* d_in, const int* in_sizes, int n_in,
                              void* d_out, int out_size, void* d_ws, size_t ws_size,
                              hipStream_t stream) {
    const float* x = (const float*)d_in[0];
    const float* should_pop = (const float*)d_in[1];
    const float* sharpen_ptr = (const float*)d_in[2];
    const float* latch_enable = (const float*)d_in[3];
    const float* latch_init = (const float*)d_in[4];
    float* out = (float*)d_out;

    const int D = in_sizes[1];          // 256
    const int B = in_sizes[4] / D;      // 128
    const int T = in_sizes[0] / in_sizes[4];  // 256

    (void)n_in; (void)out_size; (void)d_ws; (void)ws_size;

    neuralstack_kernel<<<B, 256, 0, stream>>>(x, should_pop, sharpen_ptr,
                                              latch_enable, latch_init, out, T);
}

// Round 2
// 351.559 us; speedup vs baseline: 1.3983x; 1.3983x over previous
//
#include <hip/hip_runtime.h>
#include <math.h>

// NeuralstackOnly decomposed into 5 stages:
//  K1: g[b,t]   = elu(cos(latch_enable, x[b,t,:]))            (parallel b*t)
//  K2: latch scan, store L[b,t,:] = latch used at step t       (parallel b*d)
//  K3: pop[b,t] = elu(cos(should_pop, L[b,t,:]))               (parallel b*t)
//  K4: pointer recurrence per b (serial t, 32 lanes), emits
//      per-(b,t,n): alpha,beta,gamma (stack affine) + w (readout) (128 chains)
//  K5: stack recurrence st=a*st+b*x+c and out=sum_n w*st        (parallel b*d*n)
// B=128, T=256, D=256, NSTK=32.

#define NSTK 32
#define DDIM 256
#define ZO 1e-6f
#define EPSC 1e-8f
#define PEPS 1e-12f

__device__ __forceinline__ float elu_f(float c) {
    return (c > 0.f) ? c : expm1f(c);
}

// ---------------- K1 / K3: cosine-gate reductions, block per (b,t) ----------
// mode 0: g = elu(cos(par, vec));  vec = x[b,t,:]
__global__ void gate_kernel(const float* __restrict__ vecs,   // [B,T,D]
                            const float* __restrict__ par,    // [D]
                            float* __restrict__ gout,         // [B,T]
                            int T) {
    const int t = blockIdx.x, b = blockIdx.y;
    const int tid = threadIdx.x, wave = tid >> 6, lane = tid & 63;
    __shared__ float red[4][3];
    const float v = vecs[((size_t)b * T + t) * DDIM + tid];
    const float p = par[tid];
    float r0 = p * v, r1 = v * v, r2 = p * p;
#pragma unroll
    for (int off = 32; off >= 1; off >>= 1) {
        r0 += __shfl_xor(r0, off, 64);
        r1 += __shfl_xor(r1, off, 64);
        r2 += __shfl_xor(r2, off, 64);
    }
    if (lane == 0) { red[wave][0] = r0; red[wave][1] = r1; red[wave][2] = r2; }
    __syncthreads();
    if (tid == 0) {
        float d0 = red[0][0] + red[1][0] + red[2][0] + red[3][0];
        float d1 = red[0][1] + red[1][1] + red[2][1] + red[3][1];
        float d2 = red[0][2] + red[1][2] + red[2][2] + red[3][2];
        float c = d0 / (fmaxf(sqrtf(d2), EPSC) * fmaxf(sqrtf(d1), EPSC));
        gout[(size_t)b * T + t] = elu_f(c);
    }
}

// ---------------- K2: latch scan, thread per (b,d) --------------------------
__global__ void latch_scan_kernel(const float* __restrict__ x,       // [B,T,D]
                                  const float* __restrict__ latch0,  // [B,D]
                                  const float* __restrict__ g,       // [B,T]
                                  float* __restrict__ L,             // [B,T,D]
                                  int T) {
    const int b = blockIdx.x;          // one block per batch row (256 threads=d)
    const int d = threadIdx.x;
    const float* xb = x + (size_t)b * T * DDIM + d;
    const float* gb = g + (size_t)b * T;
    float* Lb = L + (size_t)b * T * DDIM + d;
    float l = latch0[(size_t)b * DDIM + d];
    Lb[0] = l;
#pragma unroll 8
    for (int t = 0; t < T - 1; t++) {
        const float xv = xb[(size_t)t * DDIM];
        const float gt = gb[t];
        l = fmaf(gt, xv - l, l);
        Lb[(size_t)(t + 1) * DDIM] = l;
    }
}

// ---------------- K4: pointer recurrence, block per b -----------------------
// scal layout per (b,t): [alpha[32] | beta[32] | gamma[32] | w[32]]
__global__ void ptr_scan_kernel(const float* __restrict__ pop_arr,  // [B,T]
                                const float* __restrict__ sharpen_ptr,
                                float* __restrict__ scal,           // [B,T,128]
                                int T) {
    const int b = blockIdx.x;
    const int n = threadIdx.x & 31;             // lanes 32-63 mirror lanes 0-31
    const bool act = threadIdx.x < 32;
    const float sharpen = sharpen_ptr[0];
    const bool sharp5 = (sharpen == 5.0f);
    const float* popb = pop_arr + (size_t)b * T;
    float* scb = scal + (size_t)b * T * 128;

    float p = (n == 0) ? 1.0f : ZO;
    for (int t = 0; t < T; t++) {
        const float pop = popb[t];
        const float push = 1.0f - pop;
        const float pp = __shfl(p, (n + 31) & 31, 32);   // roll +1
        const float pn = __shfl(p, (n + 1) & 31, 32);    // roll -1
        float np = fmaf(push, pp, pop * pn);
        float q = fmaxf(np, PEPS);
        float q5;
        if (sharp5) { const float q2 = q * q; q5 = q2 * q2 * q; }
        else        { q5 = exp2f(sharpen * log2f(q)); }
        float s = q5;
        s += __shfl_xor(s, 16, 32);
        s += __shfl_xor(s, 8, 32);
        s += __shfl_xor(s, 4, 32);
        s += __shfl_xor(s, 2, 32);
        s += __shfl_xor(s, 1, 32);
        const float inv = 1.0f / fmaxf(s, EPSC);
        const float pnew = q5 * inv;
        if (act) {
            float* row = scb + (size_t)t * 128;
            // alpha = push*(1-pp) + pop*(1-p)
            row[n]      = fmaf(push, -pp, push) + fmaf(pop, -p, pop);
            row[32 + n] = push * pp;            // beta
            row[64 + n] = pop * p * ZO;         // gamma
            row[96 + n] = pop * pnew;           // w (pop folded into readout)
        }
        p = pnew;
    }
}

// ---------------- K5: stack recurrence + readout ----------------------------
// block: 256 threads = 4 waves; wave = 16 d x 4 n-groups (8 slots each)
__global__ void stack_kernel(const float* __restrict__ x,     // [B,T,D]
                             const float* __restrict__ scal,  // [B,T,128]
                             float* __restrict__ out,         // [B,T,D]
                             int T) {
    const int b = blockIdx.y;
    const int dtile = blockIdx.x;                 // 0..3
    const int wave = threadIdx.x >> 6;
    const int lane = threadIdx.x & 63;
    const int dsub = lane & 15;
    const int ng = lane >> 4;                     // 0..3 -> slots ng*8..ng*8+7
    const int d = dtile * 64 + wave * 16 + dsub;

    const float* xb = x + (size_t)b * T * DDIM + d;
    float* ob = out + (size_t)b * T * DDIM + d;
    const float4* sc = (const float4*)(scal + (size_t)b * T * 128);
    // per t: 32 float4; alpha at +0, beta at +8, gamma at +16, w at +24 (float4 units)

    float st[8];
#pragma unroll
    for (int j = 0; j < 8; j++) st[j] = ZO;

#pragma unroll 2
    for (int t = 0; t < T; t++) {
        const int base = t * 32 + ng * 2;
        const float4 a0 = sc[base + 0],  a1 = sc[base + 1];
        const float4 b0 = sc[base + 8],  b1 = sc[base + 9];
        const float4 g0 = sc[base + 16], g1 = sc[base + 17];
        const float4 w0 = sc[base + 24], w1 = sc[base + 25];
        const float xv = xb[(size_t)t * DDIM];

        float acc;
        st[0] = fmaf(a0.x, st[0], fmaf(b0.x, xv, g0.x)); acc  = st[0] * w0.x;
        st[1] = fmaf(a0.y, st[1], fmaf(b0.y, xv, g0.y)); acc += st[1] * w0.y;
        st[2] = fmaf(a0.z, st[2], fmaf(b0.z, xv, g0.z)); acc += st[2] * w0.z;
        st[3] = fmaf(a0.w, st[3], fmaf(b0.w, xv, g0.w)); acc += st[3] * w0.w;
        st[4] = fmaf(a1.x, st[4], fmaf(b1.x, xv, g1.x)); acc += st[4] * w1.x;
        st[5] = fmaf(a1.y, st[5], fmaf(b1.y, xv, g1.y)); acc += st[5] * w1.y;
        st[6] = fmaf(a1.z, st[6], fmaf(b1.z, xv, g1.z)); acc += st[6] * w1.z;
        st[7] = fmaf(a1.w, st[7], fmaf(b1.w, xv, g1.w)); acc += st[7] * w1.w;

        acc += __shfl_xor(acc, 16, 64);
        acc += __shfl_xor(acc, 32, 64);
        if (ng == 0) ob[(size_t)t * DDIM] = acc;
    }
}

// ---------------- Fallback: round-1 monolithic kernel -----------------------
__launch_bounds__(256, 1)
__global__ void neuralstack_kernel(const float* __restrict__ x,
                                   const float* __restrict__ should_pop,
                                   const float* __restrict__ sharpen_ptr,
                                   const float* __restrict__ latch_enable,
                                   const float* __restrict__ latch_init,
                                   float* __restrict__ out,
                                   int T) {
    const int b = blockIdx.x;
    const int tid = threadIdx.x;
    const int wave = tid >> 6;
    const int lane = tid & 63;
    __shared__ float red[2][16];
    const float sp_d = should_pop[tid];
    const float le_d = latch_enable[tid];
    const float sharpen = sharpen_ptr[0];
    float latch = latch_init[(size_t)b * DDIM + tid];
    float a0 = sp_d * sp_d, a1 = le_d * le_d;
#pragma unroll
    for (int off = 32; off >= 1; off >>= 1) {
        a0 += __shfl_xor(a0, off, 64);
        a1 += __shfl_xor(a1, off, 64);
    }
    if (lane == 0) { red[0][wave * 4] = a0; red[0][wave * 4 + 1] = a1; }
    __syncthreads();
    const float an_sp = fmaxf(sqrtf(red[0][0] + red[0][4] + red[0][8] + red[0][12]), EPSC);
    const float an_le = fmaxf(sqrtf(red[0][1] + red[0][5] + red[0][9] + red[0][13]), EPSC);
    __syncthreads();
    float st[NSTK], ptr[NSTK];
#pragma unroll
    for (int n = 0; n < NSTK; n++) { st[n] = ZO; ptr[n] = (n == 0) ? 1.0f : ZO; }
    const float* xb = x + (size_t)b * T * DDIM + tid;
    float* ob = out + (size_t)b * T * DDIM + tid;
    const bool sharp5 = (sharpen == 5.0f);
    float inp = xb[0];
    for (int t = 0; t < T; t++) {
        const int tn = (t + 1 < T) ? (t + 1) : (T - 1);
        const float inp_next = xb[(size_t)tn * DDIM];
        float r0 = sp_d * latch, r1 = latch * latch, r2 = le_d * inp, r3 = inp * inp;
#pragma unroll
        for (int off = 32; off >= 1; off >>= 1) {
            r0 += __shfl_xor(r0, off, 64);
            r1 += __shfl_xor(r1, off, 64);
            r2 += __shfl_xor(r2, off, 64);
            r3 += __shfl_xor(r3, off, 64);
        }
        const int buf = t & 1;
        if (lane == 0) {
            red[buf][wave * 4] = r0; red[buf][wave * 4 + 1] = r1;
            red[buf][wave * 4 + 2] = r2; red[buf][wave * 4 + 3] = r3;
        }
        __syncthreads();
        const float s0 = red[buf][0] + red[buf][4] + red[buf][8] + red[buf][12];
        const float s1 = red[buf][1] + red[buf][5] + red[buf][9] + red[buf][13];
        const float s2 = red[buf][2] + red[buf][6] + red[buf][10] + red[buf][14];
        const float s3 = red[buf][3] + red[buf][7] + red[buf][11] + red[buf][15];
        const float c_pop = s0 / (an_sp * fmaxf(sqrtf(s1), EPSC));
        const float pop = elu_f(c_pop);
        const float push = 1.0f - pop;
        const float g = elu_f(s2 / (an_le * fmaxf(sqrtf(s3), EPSC)));
        float q[NSTK];
#pragma unroll
        for (int n = 0; n < NSTK; n++) {
            const float pp = ptr[(n + NSTK - 1) & (NSTK - 1)];
            const float pn = ptr[(n + 1) & (NSTK - 1)];
            q[n] = fmaxf(push * pp + pop * pn, PEPS);
        }
        if (sharp5) {
#pragma unroll
            for (int n = 0; n < NSTK; n++) { const float v = q[n], v2 = v * v; q[n] = v2 * v2 * v; }
        } else {
#pragma unroll
            for (int n = 0; n < NSTK; n++) q[n] = exp2f(sharpen * log2f(q[n]));
        }
        float qa = 0.f, qb = 0.f, qc = 0.f, qd = 0.f;
#pragma unroll
        for (int n = 0; n < NSTK; n += 4) { qa += q[n]; qb += q[n+1]; qc += q[n+2]; qd += q[n+3]; }
        const float inv = 1.0f / fmaxf((qa + qb) + (qc + qd), EPSC);
        float sacc = 0.f;
#pragma unroll
        for (int n = 0; n < NSTK; n++) {
            const float pp = ptr[(n + NSTK - 1) & (NSTK - 1)];
            const float pc = ptr[n];
            const float ns = push * (st[n] + pp * (inp - st[n])) + pop * (st[n] + pc * (ZO - st[n]));
            st[n] = ns;
            sacc += ns * (q[n] * inv);
        }
#pragma unroll
        for (int n = 0; n < NSTK; n++) ptr[n] = q[n] * inv;
        ob[(size_t)t * DDIM] = pop * sacc;
        latch = fmaf(g, inp - latch, latch);
        inp = inp_next;
    }
}

extern "C" void kernel_launch(void* const* d_in, const int* in_sizes, int n_in,
                              void* d_out, int out_size, void* d_ws, size_t ws_size,
                              hipStream_t stream) {
    const float* x = (const float*)d_in[0];
    const float* should_pop = (const float*)d_in[1];
    const float* sharpen_ptr = (const float*)d_in[2];
    const float* latch_enable = (const float*)d_in[3];
    const float* latch_init = (const float*)d_in[4];
    float* out = (float*)d_out;

    const int D = in_sizes[1];                 // 256
    const int B = in_sizes[4] / D;             // 128
    const int T = in_sizes[0] / in_sizes[4];   // 256
    (void)n_in; (void)out_size;

    const size_t BT = (size_t)B * T;
    const size_t off_g = 0;
    const size_t off_pop = BT;                     // in floats
    const size_t off_L = 2 * BT;
    const size_t off_scal = off_L + BT * D;
    const size_t need_floats = off_scal + BT * 128;

    if (ws_size < need_floats * sizeof(float) || D != DDIM) {
        // fallback: monolithic scan (correct, slower)
        neuralstack_kernel<<<B, 256, 0, stream>>>(x, should_pop, sharpen_ptr,
                                                  latch_enable, latch_init, out, T);
        return;
    }

    float* ws = (float*)d_ws;
    float* g = ws + off_g;
    float* pop = ws + off_pop;
    float* L = ws + off_L;
    float* scal = ws + off_scal;

    gate_kernel<<<dim3(T, B), 256, 0, stream>>>(x, latch_enable, g, T);
    latch_scan_kernel<<<B, 256, 0, stream>>>(x, latch_init, g, L, T);
    gate_kernel<<<dim3(T, B), 256, 0, stream>>>(L, should_pop, pop, T);
    ptr_scan_kernel<<<B, 64, 0, stream>>>(pop, sharpen_ptr, scal, T);
    stack_kernel<<<dim3(D / 64, B), 256, 0, stream>>>(x, scal, out, T);
}

// Round 3
// 260.859 us; speedup vs baseline: 1.8844x; 1.3477x over previous
//
#include <hip/hip_runtime.h>
#include <math.h>

// NeuralstackOnly, 5-stage decomposition (R3: latency-hiding pass):
//  K1: g[b,t]   = elu(cos(latch_enable, x[b,t,:]))   wave-per-t, float4
//  K2: latch scan -> L[b,t,:]                         chunked load batching
//  K3: pop[b,t] = elu(cos(should_pop, L[b,t,:]))      wave-per-t, float4
//  K4: pointer recurrence -> scal[b,t,128]            unchanged (serial, small)
//  K5: stack recurrence + readout                     LDS double-buffered tiles
// B=128, T=256, D=256, NSTK=32.

#define NSTK 32
#define DDIM 256
#define ZO 1e-6f
#define EPSC 1e-8f
#define PEPS 1e-12f
#define TTILE 32

__device__ __forceinline__ float elu_f(float c) {
    return (c > 0.f) ? c : expm1f(c);
}

// ---------------- K1 / K3: wave-per-t cosine gate ---------------------------
// block = 4 waves, wave w handles t = blockIdx.x*4 + w; lane covers 4 d's.
__global__ void gate4_kernel(const float* __restrict__ vecs,   // [B,T,D]
                             const float* __restrict__ par,    // [D]
                             float* __restrict__ gout,         // [B,T]
                             int T) {
    const int b = blockIdx.y;
    const int t = blockIdx.x * 4 + (threadIdx.x >> 6);
    const int lane = threadIdx.x & 63;
    const float4 v = *(const float4*)(vecs + ((size_t)b * T + t) * DDIM + lane * 4);
    const float4 p = *(const float4*)(par + lane * 4);
    float r0 = v.x * p.x + v.y * p.y + v.z * p.z + v.w * p.w;
    float r1 = v.x * v.x + v.y * v.y + v.z * v.z + v.w * v.w;
    float r2 = p.x * p.x + p.y * p.y + p.z * p.z + p.w * p.w;
#pragma unroll
    for (int off = 32; off >= 1; off >>= 1) {
        r0 += __shfl_xor(r0, off, 64);
        r1 += __shfl_xor(r1, off, 64);
        r2 += __shfl_xor(r2, off, 64);
    }
    if (lane == 0) {
        const float c = r0 / (fmaxf(sqrtf(r2), EPSC) * fmaxf(sqrtf(r1), EPSC));
        gout[(size_t)b * T + t] = elu_f(c);
    }
}

// ---------------- K2: latch scan, chunked load batching ---------------------
// grid = B*4 blocks of 64 threads; block covers (b, 64-d tile).
__global__ void latch_scan_kernel(const float* __restrict__ x,       // [B,T,D]
                                  const float* __restrict__ latch0,  // [B,D]
                                  const float* __restrict__ g,       // [B,T]
                                  float* __restrict__ L,             // [B,T,D]
                                  int T) {
    const int b = blockIdx.x >> 2;
    const int dt = blockIdx.x & 3;
    const int d = dt * 64 + threadIdx.x;
    const float* xb = x + (size_t)b * T * DDIM + d;
    const float* gb = g + (size_t)b * T;
    float* Lb = L + (size_t)b * T * DDIM + d;
    float l = latch0[(size_t)b * DDIM + d];
    for (int c = 0; c < T; c += 32) {
        float xv[32], gv[32];
#pragma unroll
        for (int i = 0; i < 32; i++) xv[i] = xb[(size_t)(c + i) * DDIM];
#pragma unroll
        for (int i = 0; i < 32; i++) gv[i] = gb[c + i];
#pragma unroll
        for (int i = 0; i < 32; i++) {
            Lb[(size_t)(c + i) * DDIM] = l;           // latch ENTERING step c+i
            l = fmaf(gv[i], xv[i] - l, l);
        }
    }
}

// ---------------- K4: pointer recurrence, block per b -----------------------
// scal layout per (b,t): [alpha[32] | beta[32] | gamma[32] | w[32]]
__global__ void ptr_scan_kernel(const float* __restrict__ pop_arr,  // [B,T]
                                const float* __restrict__ sharpen_ptr,
                                float* __restrict__ scal,           // [B,T,128]
                                int T) {
    const int b = blockIdx.x;
    const int n = threadIdx.x & 31;             // lanes 32-63 mirror lanes 0-31
    const bool act = threadIdx.x < 32;
    const float sharpen = sharpen_ptr[0];
    const bool sharp5 = (sharpen == 5.0f);
    const float* popb = pop_arr + (size_t)b * T;
    float* scb = scal + (size_t)b * T * 128;

    float p = (n == 0) ? 1.0f : ZO;
    for (int t = 0; t < T; t++) {
        const float pop = popb[t];
        const float push = 1.0f - pop;
        const float pp = __shfl(p, (n + 31) & 31, 32);   // roll +1
        const float pn = __shfl(p, (n + 1) & 31, 32);    // roll -1
        float np = fmaf(push, pp, pop * pn);
        float q = fmaxf(np, PEPS);
        float q5;
        if (sharp5) { const float q2 = q * q; q5 = q2 * q2 * q; }
        else        { q5 = exp2f(sharpen * log2f(q)); }
        float s = q5;
        s += __shfl_xor(s, 16, 32);
        s += __shfl_xor(s, 8, 32);
        s += __shfl_xor(s, 4, 32);
        s += __shfl_xor(s, 2, 32);
        s += __shfl_xor(s, 1, 32);
        const float inv = 1.0f / fmaxf(s, EPSC);
        const float pnew = q5 * inv;
        if (act) {
            float* row = scb + (size_t)t * 128;
            row[n]      = fmaf(push, -pp, push) + fmaf(pop, -p, pop);  // alpha
            row[32 + n] = push * pp;            // beta
            row[64 + n] = pop * p * ZO;         // gamma
            row[96 + n] = pop * pnew;           // w (pop folded into readout)
        }
        p = pnew;
    }
}

// ---------------- K5: stack recurrence + readout, LDS double-buffered -------
// block: 256 threads = 4 waves; wave = 16 d x 4 n-groups (8 slots each)
__launch_bounds__(256, 2)
__global__ void stack_kernel(const float* __restrict__ x,     // [B,T,D]
                             const float* __restrict__ scal,  // [B,T,128]
                             float* __restrict__ out,         // [B,T,D]
                             int T) {
    const int b = blockIdx.y;
    const int dtile = blockIdx.x;                 // 0..3
    const int tid = threadIdx.x;
    const int wave = tid >> 6;
    const int lane = tid & 63;
    const int dsub = lane & 15;
    const int ng = lane >> 4;                     // slots ng*8..ng*8+7

    __shared__ float sc_s[2][TTILE * 128];        // 2 x 16 KB
    __shared__ float x_s[2][TTILE * 64];          // 2 x 8 KB

    const float* scb = scal + (size_t)b * T * 128;
    const float* xtb = x + (size_t)b * T * DDIM + dtile * 64;
    float* ob = out + (size_t)b * T * DDIM + dtile * 64 + wave * 16 + dsub;

    // staging mapping: scal tile = 1024 float4 (4/thread);
    // x tile [32][64] = 512 float4 (2/thread): f -> trow=f>>4, dq=f&15
    const int f0 = tid, f1 = tid + 256;
    const int tr0 = f0 >> 4, dq0 = (f0 & 15) * 4;
    const int tr1 = f1 >> 4, dq1 = (f1 & 15) * 4;

    float4 sreg[4], xreg[2];

    auto load_tile = [&](int t0) {
        const float4* sg = (const float4*)(scb + (size_t)t0 * 128);
        sreg[0] = sg[tid];
        sreg[1] = sg[tid + 256];
        sreg[2] = sg[tid + 512];
        sreg[3] = sg[tid + 768];
        xreg[0] = *(const float4*)(xtb + (size_t)(t0 + tr0) * DDIM + dq0);
        xreg[1] = *(const float4*)(xtb + (size_t)(t0 + tr1) * DDIM + dq1);
    };
    auto store_tile = [&](int buf) {
        float4* ss = (float4*)sc_s[buf];
        ss[tid] = sreg[0];
        ss[tid + 256] = sreg[1];
        ss[tid + 512] = sreg[2];
        ss[tid + 768] = sreg[3];
        float4* xs = (float4*)x_s[buf];
        xs[f0] = xreg[0];
        xs[f1] = xreg[1];
    };

    float st[8];
#pragma unroll
    for (int j = 0; j < 8; j++) st[j] = ZO;

    load_tile(0);
    store_tile(0);
    __syncthreads();

    const int NT = T / TTILE;
    for (int tile = 0; tile < NT; tile++) {
        if (tile + 1 < NT) load_tile((tile + 1) * TTILE);   // prefetch (regs)
        const float* scl = sc_s[tile & 1];
        const float* xl = x_s[tile & 1] + wave * 16 + dsub;
        const int tglob = tile * TTILE;
#pragma unroll 4
        for (int tl = 0; tl < TTILE; tl++) {
            const float4* sc4 = (const float4*)(scl + tl * 128) + ng * 2;
            const float4 a0 = sc4[0],  a1 = sc4[1];
            const float4 b0 = sc4[8],  b1 = sc4[9];
            const float4 g0 = sc4[16], g1 = sc4[17];
            const float4 w0 = sc4[24], w1 = sc4[25];
            const float xv = xl[tl * 64];

            float acc;
            st[0] = fmaf(a0.x, st[0], fmaf(b0.x, xv, g0.x)); acc  = st[0] * w0.x;
            st[1] = fmaf(a0.y, st[1], fmaf(b0.y, xv, g0.y)); acc += st[1] * w0.y;
            st[2] = fmaf(a0.z, st[2], fmaf(b0.z, xv, g0.z)); acc += st[2] * w0.z;
            st[3] = fmaf(a0.w, st[3], fmaf(b0.w, xv, g0.w)); acc += st[3] * w0.w;
            st[4] = fmaf(a1.x, st[4], fmaf(b1.x, xv, g1.x)); acc += st[4] * w1.x;
            st[5] = fmaf(a1.y, st[5], fmaf(b1.y, xv, g1.y)); acc += st[5] * w1.y;
            st[6] = fmaf(a1.z, st[6], fmaf(b1.z, xv, g1.z)); acc += st[6] * w1.z;
            st[7] = fmaf(a1.w, st[7], fmaf(b1.w, xv, g1.w)); acc += st[7] * w1.w;

            acc += __shfl_xor(acc, 16, 64);
            acc += __shfl_xor(acc, 32, 64);
            if (ng == 0) ob[(size_t)(tglob + tl) * DDIM] = acc;
        }
        if (tile + 1 < NT) store_tile((tile + 1) & 1);       // regs -> LDS
        __syncthreads();
    }
}

// ---------------- Fallback: monolithic kernel (correct, slower) -------------
__launch_bounds__(256, 1)
__global__ void neuralstack_kernel(const float* __restrict__ x,
                                   const float* __restrict__ should_pop,
                                   const float* __restrict__ sharpen_ptr,
                                   const float* __restrict__ latch_enable,
                                   const float* __restrict__ latch_init,
                                   float* __restrict__ out,
                                   int T) {
    const int b = blockIdx.x;
    const int tid = threadIdx.x;
    const int wave = tid >> 6;
    const int lane = tid & 63;
    __shared__ float red[2][16];
    const float sp_d = should_pop[tid];
    const float le_d = latch_enable[tid];
    const float sharpen = sharpen_ptr[0];
    float latch = latch_init[(size_t)b * DDIM + tid];
    float a0 = sp_d * sp_d, a1 = le_d * le_d;
#pragma unroll
    for (int off = 32; off >= 1; off >>= 1) {
        a0 += __shfl_xor(a0, off, 64);
        a1 += __shfl_xor(a1, off, 64);
    }
    if (lane == 0) { red[0][wave * 4] = a0; red[0][wave * 4 + 1] = a1; }
    __syncthreads();
    const float an_sp = fmaxf(sqrtf(red[0][0] + red[0][4] + red[0][8] + red[0][12]), EPSC);
    const float an_le = fmaxf(sqrtf(red[0][1] + red[0][5] + red[0][9] + red[0][13]), EPSC);
    __syncthreads();
    float st[NSTK], ptr[NSTK];
#pragma unroll
    for (int n = 0; n < NSTK; n++) { st[n] = ZO; ptr[n] = (n == 0) ? 1.0f : ZO; }
    const float* xb = x + (size_t)b * T * DDIM + tid;
    float* ob = out + (size_t)b * T * DDIM + tid;
    const bool sharp5 = (sharpen == 5.0f);
    float inp = xb[0];
    for (int t = 0; t < T; t++) {
        const int tn = (t + 1 < T) ? (t + 1) : (T - 1);
        const float inp_next = xb[(size_t)tn * DDIM];
        float r0 = sp_d * latch, r1 = latch * latch, r2 = le_d * inp, r3 = inp * inp;
#pragma unroll
        for (int off = 32; off >= 1; off >>= 1) {
            r0 += __shfl_xor(r0, off, 64);
            r1 += __shfl_xor(r1, off, 64);
            r2 += __shfl_xor(r2, off, 64);
            r3 += __shfl_xor(r3, off, 64);
        }
        const int buf = t & 1;
        if (lane == 0) {
            red[buf][wave * 4] = r0; red[buf][wave * 4 + 1] = r1;
            red[buf][wave * 4 + 2] = r2; red[buf][wave * 4 + 3] = r3;
        }
        __syncthreads();
        const float s0 = red[buf][0] + red[buf][4] + red[buf][8] + red[buf][12];
        const float s1 = red[buf][1] + red[buf][5] + red[buf][9] + red[buf][13];
        const float s2 = red[buf][2] + red[buf][6] + red[buf][10] + red[buf][14];
        const float s3 = red[buf][3] + red[buf][7] + red[buf][11] + red[buf][15];
        const float pop = elu_f(s0 / (an_sp * fmaxf(sqrtf(s1), EPSC)));
        const float push = 1.0f - pop;
        const float g = elu_f(s2 / (an_le * fmaxf(sqrtf(s3), EPSC)));
        float q[NSTK];
#pragma unroll
        for (int n = 0; n < NSTK; n++) {
            const float pp = ptr[(n + NSTK - 1) & (NSTK - 1)];
            const float pn = ptr[(n + 1) & (NSTK - 1)];
            q[n] = fmaxf(push * pp + pop * pn, PEPS);
        }
        if (sharp5) {
#pragma unroll
            for (int n = 0; n < NSTK; n++) { const float v = q[n], v2 = v * v; q[n] = v2 * v2 * v; }
        } else {
#pragma unroll
            for (int n = 0; n < NSTK; n++) q[n] = exp2f(sharpen * log2f(q[n]));
        }
        float qa = 0.f, qb = 0.f, qc = 0.f, qd = 0.f;
#pragma unroll
        for (int n = 0; n < NSTK; n += 4) { qa += q[n]; qb += q[n+1]; qc += q[n+2]; qd += q[n+3]; }
        const float inv = 1.0f / fmaxf((qa + qb) + (qc + qd), EPSC);
        float sacc = 0.f;
#pragma unroll
        for (int n = 0; n < NSTK; n++) {
            const float pp = ptr[(n + NSTK - 1) & (NSTK - 1)];
            const float pc = ptr[n];
            const float ns = push * (st[n] + pp * (inp - st[n])) + pop * (st[n] + pc * (ZO - st[n]));
            st[n] = ns;
            sacc += ns * (q[n] * inv);
        }
#pragma unroll
        for (int n = 0; n < NSTK; n++) ptr[n] = q[n] * inv;
        ob[(size_t)t * DDIM] = pop * sacc;
        latch = fmaf(g, inp - latch, latch);
        inp = inp_next;
    }
}

extern "C" void kernel_launch(void* const* d_in, const int* in_sizes, int n_in,
                              void* d_out, int out_size, void* d_ws, size_t ws_size,
                              hipStream_t stream) {
    const float* x = (const float*)d_in[0];
    const float* should_pop = (const float*)d_in[1];
    const float* sharpen_ptr = (const float*)d_in[2];
    const float* latch_enable = (const float*)d_in[3];
    const float* latch_init = (const float*)d_in[4];
    float* out = (float*)d_out;

    const int D = in_sizes[1];                 // 256
    const int B = in_sizes[4] / D;             // 128
    const int T = in_sizes[0] / in_sizes[4];   // 256
    (void)n_in; (void)out_size;

    const size_t BT = (size_t)B * T;
    const size_t off_g = 0;
    const size_t off_pop = BT;
    const size_t off_L = 2 * BT;
    const size_t off_scal = off_L + BT * D;
    const size_t need_floats = off_scal + BT * 128;

    if (ws_size < need_floats * sizeof(float) || D != DDIM ||
        (T % TTILE) != 0 || (T % 4) != 0) {
        neuralstack_kernel<<<B, 256, 0, stream>>>(x, should_pop, sharpen_ptr,
                                                  latch_enable, latch_init, out, T);
        return;
    }

    float* ws = (float*)d_ws;
    float* g = ws + off_g;
    float* pop = ws + off_pop;
    float* L = ws + off_L;
    float* scal = ws + off_scal;

    gate4_kernel<<<dim3(T / 4, B), 256, 0, stream>>>(x, latch_enable, g, T);
    latch_scan_kernel<<<B * 4, 64, 0, stream>>>(x, latch_init, g, L, T);
    gate4_kernel<<<dim3(T / 4, B), 256, 0, stream>>>(L, should_pop, pop, T);
    ptr_scan_kernel<<<B, 64, 0, stream>>>(pop, sharpen_ptr, scal, T);
    stack_kernel<<<dim3(D / 64, B), 256, 0, stream>>>(x, scal, out, T);
}

// Round 4
// 227.301 us; speedup vs baseline: 2.1627x; 1.1476x over previous
//
#include <hip/hip_runtime.h>
#include <math.h>

// NeuralstackOnly, 5-stage decomposition (R4: ptr-scan critical-path pass):
//  K1: g[b,t]   = elu(cos(latch_enable, x[b,t,:]))   wave-per-t, float4
//  K2: latch scan -> L[b,t,:]                         chunked load batching
//  K3: pop[b,t] = elu(cos(should_pop, L[b,t,:]))      wave-per-t, float4
//  K4: pointer recurrence -> scal[b,t,128]            DPP tree + deferred norm
//  K5: stack recurrence + readout                     LDS double-buffered tiles
// B=128, T=256, D=256, NSTK=32.

#define NSTK 32
#define DDIM 256
#define ZO 1e-6f
#define EPSC 1e-8f
#define PEPS 1e-12f
#define TTILE 32
#define MAXT 1024

__device__ __forceinline__ float elu_f(float c) {
    return (c > 0.f) ? c : expm1f(c);
}

// DPP cross-lane helpers (pairing permutations for sum-reduce, groups of 32)
__device__ __forceinline__ float dpp_xor1(float x) {   // quad_perm [1,0,3,2]
    return __int_as_float(__builtin_amdgcn_update_dpp(0, __float_as_int(x), 0xB1, 0xF, 0xF, true));
}
__device__ __forceinline__ float dpp_xor2(float x) {   // quad_perm [2,3,0,1]
    return __int_as_float(__builtin_amdgcn_update_dpp(0, __float_as_int(x), 0x4E, 0xF, 0xF, true));
}
__device__ __forceinline__ float dpp_halfmirror(float x) {  // row_half_mirror
    return __int_as_float(__builtin_amdgcn_update_dpp(0, __float_as_int(x), 0x141, 0xF, 0xF, true));
}
__device__ __forceinline__ float dpp_mirror(float x) {      // row_mirror
    return __int_as_float(__builtin_amdgcn_update_dpp(0, __float_as_int(x), 0x140, 0xF, 0xF, true));
}
__device__ __forceinline__ float swz_xor16(float x) {  // lane ^= 16 within 32
    return __int_as_float(__builtin_amdgcn_ds_swizzle(__float_as_int(x), 0x401F));
}

// ---------------- K1 / K3: wave-per-t cosine gate ---------------------------
__global__ void gate4_kernel(const float* __restrict__ vecs,   // [B,T,D]
                             const float* __restrict__ par,    // [D]
                             float* __restrict__ gout,         // [B,T]
                             int T) {
    const int b = blockIdx.y;
    const int t = blockIdx.x * 4 + (threadIdx.x >> 6);
    const int lane = threadIdx.x & 63;
    const float4 v = *(const float4*)(vecs + ((size_t)b * T + t) * DDIM + lane * 4);
    const float4 p = *(const float4*)(par + lane * 4);
    float r0 = v.x * p.x + v.y * p.y + v.z * p.z + v.w * p.w;
    float r1 = v.x * v.x + v.y * v.y + v.z * v.z + v.w * v.w;
    float r2 = p.x * p.x + p.y * p.y + p.z * p.z + p.w * p.w;
#pragma unroll
    for (int off = 32; off >= 1; off >>= 1) {
        r0 += __shfl_xor(r0, off, 64);
        r1 += __shfl_xor(r1, off, 64);
        r2 += __shfl_xor(r2, off, 64);
    }
    if (lane == 0) {
        const float c = r0 / (fmaxf(sqrtf(r2), EPSC) * fmaxf(sqrtf(r1), EPSC));
        gout[(size_t)b * T + t] = elu_f(c);
    }
}

// ---------------- K2: latch scan, chunked load batching ---------------------
__global__ void latch_scan_kernel(const float* __restrict__ x,       // [B,T,D]
                                  const float* __restrict__ latch0,  // [B,D]
                                  const float* __restrict__ g,       // [B,T]
                                  float* __restrict__ L,             // [B,T,D]
                                  int T) {
    const int b = blockIdx.x >> 2;
    const int dt = blockIdx.x & 3;
    const int d = dt * 64 + threadIdx.x;
    const float* xb = x + (size_t)b * T * DDIM + d;
    const float* gb = g + (size_t)b * T;
    float* Lb = L + (size_t)b * T * DDIM + d;
    float l = latch0[(size_t)b * DDIM + d];
    for (int c = 0; c < T; c += 32) {
        float xv[32], gv[32];
#pragma unroll
        for (int i = 0; i < 32; i++) xv[i] = xb[(size_t)(c + i) * DDIM];
#pragma unroll
        for (int i = 0; i < 32; i++) gv[i] = gb[c + i];
#pragma unroll
        for (int i = 0; i < 32; i++) {
            Lb[(size_t)(c + i) * DDIM] = l;           // latch ENTERING step c+i
            l = fmaf(gv[i], xv[i] - l, l);
        }
    }
}

// ---------------- K4: pointer recurrence, 2 b per wave ----------------------
// scal layout per (b,t): [alpha[32] | beta[32] | gamma[32] | w[32]]
// Deferred normalization: carry u = q^5 (unnormalized) + invu = 1/sum.
__launch_bounds__(64, 1)
__global__ void ptr_scan_kernel(const float* __restrict__ pop_arr,  // [B,T]
                                const float* __restrict__ sharpen_ptr,
                                float* __restrict__ scal,           // [B,T,128]
                                int T) {
    const int b0 = blockIdx.x * 2;
    const int tid = threadIdx.x;
    const int n = tid & 31;
    const int grp = tid >> 5;                  // 0/1 -> which b
    const float sharpen = sharpen_ptr[0];
    const bool sharp5 = (sharpen == 5.0f);

    __shared__ float pops[2 * MAXT];
    for (int i = tid; i < 2 * T; i += 64) pops[i] = pop_arr[(size_t)b0 * T + i];
    __syncthreads();
    const float* popg = pops + grp * T;

    float* scb = scal + (size_t)(b0 + grp) * T * 128;

    float u = (n == 0) ? 1.0f : ZO;    // unnormalized pointer entering step t
    float invu = 1.0f;                 // its normalizer (p = u * invu)

#pragma unroll 2
    for (int t = 0; t < T; t++) {
        const float pop = popg[t];
        const float push = 1.0f - pop;
        // rolls of u (concurrent with nothing yet; merge with invu below)
        const float up = __shfl(u, (n + 31) & 31, 32);   // roll +1
        const float un = __shfl(u, (n + 1) & 31, 32);    // roll -1
        const float r = fmaf(push, up, pop * un);
        const float np = r * invu;                       // normalized combine
        const float q = fmaxf(np, PEPS);
        float unew;
        if (sharp5) { const float q2 = q * q, q4 = q2 * q2; unew = q4 * q; }
        else        { unew = exp2f(sharpen * log2f(q)); }
        // sum over 32 slots: 4 DPP pair-adds + 1 swizzle
        float s = unew;
        s += dpp_xor1(s);
        s += dpp_xor2(s);
        s += dpp_halfmirror(s);
        s += dpp_mirror(s);
        s += swz_xor16(s);
        const float invn = 1.0f / fmaxf(s, EPSC);
        // coefficients (off the u-chain; issue in tree's latency shadow)
        const float p = u * invu;
        const float ppn = up * invu;
        const float pnew = unew * invn;
        float* row = scb + (size_t)t * 128;
        row[n]      = fmaf(push, -ppn, push) + fmaf(pop, -p, pop);  // alpha
        row[32 + n] = push * ppn;                                   // beta
        row[64 + n] = pop * p * ZO;                                 // gamma
        row[96 + n] = pop * pnew;                                   // w
        u = unew; invu = invn;
    }
}

// ---------------- K5: stack recurrence + readout, LDS double-buffered -------
__launch_bounds__(256, 2)
__global__ void stack_kernel(const float* __restrict__ x,     // [B,T,D]
                             const float* __restrict__ scal,  // [B,T,128]
                             float* __restrict__ out,         // [B,T,D]
                             int T) {
    const int b = blockIdx.y;
    const int dtile = blockIdx.x;                 // 0..3
    const int tid = threadIdx.x;
    const int wave = tid >> 6;
    const int lane = tid & 63;
    const int dsub = lane & 15;
    const int ng = lane >> 4;                     // slots ng*8..ng*8+7

    __shared__ float sc_s[2][TTILE * 128];        // 2 x 16 KB
    __shared__ float x_s[2][TTILE * 64];          // 2 x 8 KB

    const float* scb = scal + (size_t)b * T * 128;
    const float* xtb = x + (size_t)b * T * DDIM + dtile * 64;
    float* ob = out + (size_t)b * T * DDIM + dtile * 64 + wave * 16 + dsub;

    const int f0 = tid, f1 = tid + 256;
    const int tr0 = f0 >> 4, dq0 = (f0 & 15) * 4;
    const int tr1 = f1 >> 4, dq1 = (f1 & 15) * 4;

    float4 sreg[4], xreg[2];

    auto load_tile = [&](int t0) {
        const float4* sg = (const float4*)(scb + (size_t)t0 * 128);
        sreg[0] = sg[tid];
        sreg[1] = sg[tid + 256];
        sreg[2] = sg[tid + 512];
        sreg[3] = sg[tid + 768];
        xreg[0] = *(const float4*)(xtb + (size_t)(t0 + tr0) * DDIM + dq0);
        xreg[1] = *(const float4*)(xtb + (size_t)(t0 + tr1) * DDIM + dq1);
    };
    auto store_tile = [&](int buf) {
        float4* ss = (float4*)sc_s[buf];
        ss[tid] = sreg[0];
        ss[tid + 256] = sreg[1];
        ss[tid + 512] = sreg[2];
        ss[tid + 768] = sreg[3];
        float4* xs = (float4*)x_s[buf];
        xs[f0] = xreg[0];
        xs[f1] = xreg[1];
    };

    float st[8];
#pragma unroll
    for (int j = 0; j < 8; j++) st[j] = ZO;

    load_tile(0);
    store_tile(0);
    __syncthreads();

    const int NT = T / TTILE;
    for (int tile = 0; tile < NT; tile++) {
        if (tile + 1 < NT) load_tile((tile + 1) * TTILE);   // prefetch (regs)
        const float* scl = sc_s[tile & 1];
        const float* xl = x_s[tile & 1] + wave * 16 + dsub;
        const int tglob = tile * TTILE;
#pragma unroll 4
        for (int tl = 0; tl < TTILE; tl++) {
            const float4* sc4 = (const float4*)(scl + tl * 128) + ng * 2;
            const float4 a0 = sc4[0],  a1 = sc4[1];
            const float4 b0 = sc4[8],  b1 = sc4[9];
            const float4 g0 = sc4[16], g1 = sc4[17];
            const float4 w0 = sc4[24], w1 = sc4[25];
            const float xv = xl[tl * 64];

            float acc;
            st[0] = fmaf(a0.x, st[0], fmaf(b0.x, xv, g0.x)); acc  = st[0] * w0.x;
            st[1] = fmaf(a0.y, st[1], fmaf(b0.y, xv, g0.y)); acc += st[1] * w0.y;
            st[2] = fmaf(a0.z, st[2], fmaf(b0.z, xv, g0.z)); acc += st[2] * w0.z;
            st[3] = fmaf(a0.w, st[3], fmaf(b0.w, xv, g0.w)); acc += st[3] * w0.w;
            st[4] = fmaf(a1.x, st[4], fmaf(b1.x, xv, g1.x)); acc += st[4] * w1.x;
            st[5] = fmaf(a1.y, st[5], fmaf(b1.y, xv, g1.y)); acc += st[5] * w1.y;
            st[6] = fmaf(a1.z, st[6], fmaf(b1.z, xv, g1.z)); acc += st[6] * w1.z;
            st[7] = fmaf(a1.w, st[7], fmaf(b1.w, xv, g1.w)); acc += st[7] * w1.w;

            acc += __shfl_xor(acc, 16, 64);
            acc += __shfl_xor(acc, 32, 64);
            if (ng == 0) ob[(size_t)(tglob + tl) * DDIM] = acc;
        }
        if (tile + 1 < NT) store_tile((tile + 1) & 1);       // regs -> LDS
        __syncthreads();
    }
}

// ---------------- Fallback: monolithic kernel (correct, slower) -------------
__launch_bounds__(256, 1)
__global__ void neuralstack_kernel(const float* __restrict__ x,
                                   const float* __restrict__ should_pop,
                                   const float* __restrict__ sharpen_ptr,
                                   const float* __restrict__ latch_enable,
                                   const float* __restrict__ latch_init,
                                   float* __restrict__ out,
                                   int T) {
    const int b = blockIdx.x;
    const int tid = threadIdx.x;
    const int wave = tid >> 6;
    const int lane = tid & 63;
    __shared__ float red[2][16];
    const float sp_d = should_pop[tid];
    const float le_d = latch_enable[tid];
    const float sharpen = sharpen_ptr[0];
    float latch = latch_init[(size_t)b * DDIM + tid];
    float a0 = sp_d * sp_d, a1 = le_d * le_d;
#pragma unroll
    for (int off = 32; off >= 1; off >>= 1) {
        a0 += __shfl_xor(a0, off, 64);
        a1 += __shfl_xor(a1, off, 64);
    }
    if (lane == 0) { red[0][wave * 4] = a0; red[0][wave * 4 + 1] = a1; }
    __syncthreads();
    const float an_sp = fmaxf(sqrtf(red[0][0] + red[0][4] + red[0][8] + red[0][12]), EPSC);
    const float an_le = fmaxf(sqrtf(red[0][1] + red[0][5] + red[0][9] + red[0][13]), EPSC);
    __syncthreads();
    float st[NSTK], ptr[NSTK];
#pragma unroll
    for (int n = 0; n < NSTK; n++) { st[n] = ZO; ptr[n] = (n == 0) ? 1.0f : ZO; }
    const float* xb = x + (size_t)b * T * DDIM + tid;
    float* ob = out + (size_t)b * T * DDIM + tid;
    const bool sharp5 = (sharpen == 5.0f);
    float inp = xb[0];
    for (int t = 0; t < T; t++) {
        const int tn = (t + 1 < T) ? (t + 1) : (T - 1);
        const float inp_next = xb[(size_t)tn * DDIM];
        float r0 = sp_d * latch, r1 = latch * latch, r2 = le_d * inp, r3 = inp * inp;
#pragma unroll
        for (int off = 32; off >= 1; off >>= 1) {
            r0 += __shfl_xor(r0, off, 64);
            r1 += __shfl_xor(r1, off, 64);
            r2 += __shfl_xor(r2, off, 64);
            r3 += __shfl_xor(r3, off, 64);
        }
        const int buf = t & 1;
        if (lane == 0) {
            red[buf][wave * 4] = r0; red[buf][wave * 4 + 1] = r1;
            red[buf][wave * 4 + 2] = r2; red[buf][wave * 4 + 3] = r3;
        }
        __syncthreads();
        const float s0 = red[buf][0] + red[buf][4] + red[buf][8] + red[buf][12];
        const float s1 = red[buf][1] + red[buf][5] + red[buf][9] + red[buf][13];
        const float s2 = red[buf][2] + red[buf][6] + red[buf][10] + red[buf][14];
        const float s3 = red[buf][3] + red[buf][7] + red[buf][11] + red[buf][15];
        const float pop = elu_f(s0 / (an_sp * fmaxf(sqrtf(s1), EPSC)));
        const float push = 1.0f - pop;
        const float g = elu_f(s2 / (an_le * fmaxf(sqrtf(s3), EPSC)));
        float q[NSTK];
#pragma unroll
        for (int n = 0; n < NSTK; n++) {
            const float pp = ptr[(n + NSTK - 1) & (NSTK - 1)];
            const float pn = ptr[(n + 1) & (NSTK - 1)];
            q[n] = fmaxf(push * pp + pop * pn, PEPS);
        }
        if (sharp5) {
#pragma unroll
            for (int n = 0; n < NSTK; n++) { const float v = q[n], v2 = v * v; q[n] = v2 * v2 * v; }
        } else {
#pragma unroll
            for (int n = 0; n < NSTK; n++) q[n] = exp2f(sharpen * log2f(q[n]));
        }
        float qa = 0.f, qb = 0.f, qc = 0.f, qd = 0.f;
#pragma unroll
        for (int n = 0; n < NSTK; n += 4) { qa += q[n]; qb += q[n+1]; qc += q[n+2]; qd += q[n+3]; }
        const float inv = 1.0f / fmaxf((qa + qb) + (qc + qd), EPSC);
        float sacc = 0.f;
#pragma unroll
        for (int n = 0; n < NSTK; n++) {
            const float pp = ptr[(n + NSTK - 1) & (NSTK - 1)];
            const float pc = ptr[n];
            const float ns = push * (st[n] + pp * (inp - st[n])) + pop * (st[n] + pc * (ZO - st[n]));
            st[n] = ns;
            sacc += ns * (q[n] * inv);
        }
#pragma unroll
        for (int n = 0; n < NSTK; n++) ptr[n] = q[n] * inv;
        ob[(size_t)t * DDIM] = pop * sacc;
        latch = fmaf(g, inp - latch, latch);
        inp = inp_next;
    }
}

extern "C" void kernel_launch(void* const* d_in, const int* in_sizes, int n_in,
                              void* d_out, int out_size, void* d_ws, size_t ws_size,
                              hipStream_t stream) {
    const float* x = (const float*)d_in[0];
    const float* should_pop = (const float*)d_in[1];
    const float* sharpen_ptr = (const float*)d_in[2];
    const float* latch_enable = (const float*)d_in[3];
    const float* latch_init = (const float*)d_in[4];
    float* out = (float*)d_out;

    const int D = in_sizes[1];                 // 256
    const int B = in_sizes[4] / D;             // 128
    const int T = in_sizes[0] / in_sizes[4];   // 256
    (void)n_in; (void)out_size;

    const size_t BT = (size_t)B * T;
    const size_t off_g = 0;
    const size_t off_pop = BT;
    const size_t off_L = 2 * BT;
    const size_t off_scal = off_L + BT * D;
    const size_t need_floats = off_scal + BT * 128;

    if (ws_size < need_floats * sizeof(float) || D != DDIM ||
        (T % TTILE) != 0 || (T % 4) != 0 || (B % 2) != 0 || T > MAXT) {
        neuralstack_kernel<<<B, 256, 0, stream>>>(x, should_pop, sharpen_ptr,
                                                  latch_enable, latch_init, out, T);
        return;
    }

    float* ws = (float*)d_ws;
    float* g = ws + off_g;
    float* pop = ws + off_pop;
    float* L = ws + off_L;
    float* scal = ws + off_scal;

    gate4_kernel<<<dim3(T / 4, B), 256, 0, stream>>>(x, latch_enable, g, T);
    latch_scan_kernel<<<B * 4, 64, 0, stream>>>(x, latch_init, g, L, T);
    gate4_kernel<<<dim3(T / 4, B), 256, 0, stream>>>(L, should_pop, pop, T);
    ptr_scan_kernel<<<B / 2, 64, 0, stream>>>(pop, sharpen_ptr, scal, T);
    stack_kernel<<<dim3(D / 64, B), 256, 0, stream>>>(x, scal, out, T);
}

// Round 5
// 224.700 us; speedup vs baseline: 2.1877x; 1.0116x over previous
//
#include <hip/hip_runtime.h>
#include <math.h>

// NeuralstackOnly, 5-stage decomposition (R5: compact P interchange):
//  K1: g[b,t]   = elu(cos(latch_enable, x[b,t,:]))   wave-per-t, float4
//  K2: latch scan -> L[b,t,:]                         chunked load batching
//  K3: pop[b,t] = elu(cos(should_pop, L[b,t,:]))      wave-per-t, float4
//  K4: pointer recurrence -> P[b,t,32]                reg-prefetched pops
//  K5: stack recurrence + readout                     single-wave blocks,
//      coefficients recomputed from P (2xb128/t instead of 8xb128/t)
// B=128, T=256, D=256, NSTK=32.

#define NSTK 32
#define DDIM 256
#define ZO 1e-6f
#define EPSC 1e-8f
#define PEPS 1e-12f
#define TTILE 32
#define MAXT 1024

__device__ __forceinline__ float elu_f(float c) {
    return (c > 0.f) ? c : expm1f(c);
}

// DPP cross-lane helpers (sum-reduce pairings within groups of 32) — verified R4
__device__ __forceinline__ float dpp_xor1(float x) {   // quad_perm [1,0,3,2]
    return __int_as_float(__builtin_amdgcn_update_dpp(0, __float_as_int(x), 0xB1, 0xF, 0xF, true));
}
__device__ __forceinline__ float dpp_xor2(float x) {   // quad_perm [2,3,0,1]
    return __int_as_float(__builtin_amdgcn_update_dpp(0, __float_as_int(x), 0x4E, 0xF, 0xF, true));
}
__device__ __forceinline__ float dpp_halfmirror(float x) {  // row_half_mirror
    return __int_as_float(__builtin_amdgcn_update_dpp(0, __float_as_int(x), 0x141, 0xF, 0xF, true));
}
__device__ __forceinline__ float dpp_mirror(float x) {      // row_mirror
    return __int_as_float(__builtin_amdgcn_update_dpp(0, __float_as_int(x), 0x140, 0xF, 0xF, true));
}
__device__ __forceinline__ float swz_xor16(float x) {  // lane ^= 16 within 32
    return __int_as_float(__builtin_amdgcn_ds_swizzle(__float_as_int(x), 0x401F));
}

// ---------------- K1 / K3: wave-per-t cosine gate ---------------------------
__global__ void gate4_kernel(const float* __restrict__ vecs,   // [B,T,D]
                             const float* __restrict__ par,    // [D]
                             float* __restrict__ gout,         // [B,T]
                             int T) {
    const int b = blockIdx.y;
    const int t = blockIdx.x * 4 + (threadIdx.x >> 6);
    const int lane = threadIdx.x & 63;
    const float4 v = *(const float4*)(vecs + ((size_t)b * T + t) * DDIM + lane * 4);
    const float4 p = *(const float4*)(par + lane * 4);
    float r0 = v.x * p.x + v.y * p.y + v.z * p.z + v.w * p.w;
    float r1 = v.x * v.x + v.y * v.y + v.z * v.z + v.w * v.w;
    float r2 = p.x * p.x + p.y * p.y + p.z * p.z + p.w * p.w;
#pragma unroll
    for (int off = 32; off >= 1; off >>= 1) {
        r0 += __shfl_xor(r0, off, 64);
        r1 += __shfl_xor(r1, off, 64);
        r2 += __shfl_xor(r2, off, 64);
    }
    if (lane == 0) {
        const float c = r0 / (fmaxf(sqrtf(r2), EPSC) * fmaxf(sqrtf(r1), EPSC));
        gout[(size_t)b * T + t] = elu_f(c);
    }
}

// ---------------- K2: latch scan, chunked load batching ---------------------
__global__ void latch_scan_kernel(const float* __restrict__ x,       // [B,T,D]
                                  const float* __restrict__ latch0,  // [B,D]
                                  const float* __restrict__ g,       // [B,T]
                                  float* __restrict__ L,             // [B,T,D]
                                  int T) {
    const int b = blockIdx.x >> 2;
    const int dt = blockIdx.x & 3;
    const int d = dt * 64 + threadIdx.x;
    const float* xb = x + (size_t)b * T * DDIM + d;
    const float* gb = g + (size_t)b * T;
    float* Lb = L + (size_t)b * T * DDIM + d;
    float l = latch0[(size_t)b * DDIM + d];
    for (int c = 0; c < T; c += 32) {
        float xv[32], gv[32];
#pragma unroll
        for (int i = 0; i < 32; i++) xv[i] = xb[(size_t)(c + i) * DDIM];
#pragma unroll
        for (int i = 0; i < 32; i++) gv[i] = gb[c + i];
#pragma unroll
        for (int i = 0; i < 32; i++) {
            Lb[(size_t)(c + i) * DDIM] = l;           // latch ENTERING step c+i
            l = fmaf(gv[i], xv[i] - l, l);
        }
    }
}

// ---------------- K4: pointer recurrence, 2 b per wave ----------------------
// Emits P[b,t,32] = normalized sharpened pointer AFTER step t (t=0..T-1).
__launch_bounds__(64, 1)
__global__ void ptr_scan_kernel(const float* __restrict__ pop_arr,  // [B,T]
                                const float* __restrict__ sharpen_ptr,
                                float* __restrict__ Parr,           // [B,T,32]
                                int T) {
    const int b0 = blockIdx.x * 2;
    const int tid = threadIdx.x;
    const int n = tid & 31;
    const int grp = tid >> 5;                  // 0/1 -> which b
    const float sharpen = sharpen_ptr[0];
    const bool sharp5 = (sharpen == 5.0f);

    __shared__ float pops[2 * MAXT];
    for (int i = tid; i < 2 * T; i += 64) pops[i] = pop_arr[(size_t)b0 * T + i];
    __syncthreads();
    const float* popg = pops + grp * T;
    float* Pb = Parr + (size_t)(b0 + grp) * T * 32;

    float u = (n == 0) ? 1.0f : ZO;    // unnormalized pointer entering step t
    float invu = 1.0f;                 // its normalizer (p = u * invu)
    int t = 0;

    auto step = [&](float pop) {
        const float push = 1.0f - pop;
        const float up = __shfl(u, (n + 31) & 31, 32);   // roll +1
        const float un = __shfl(u, (n + 1) & 31, 32);    // roll -1
        const float r = fmaf(push, up, pop * un);
        const float q = fmaxf(r * invu, PEPS);
        float unew;
        if (sharp5) { const float q2 = q * q, q4 = q2 * q2; unew = q4 * q; }
        else        { unew = exp2f(sharpen * log2f(q)); }
        float s = unew;
        s += dpp_xor1(s);
        s += dpp_xor2(s);
        s += dpp_halfmirror(s);
        s += dpp_mirror(s);
        s += swz_xor16(s);
        const float invn = 1.0f / fmaxf(s, EPSC);
        Pb[(size_t)t * 32 + n] = unew * invn;
        u = unew; invu = invn;
        t++;
    };

    const float4* p4 = (const float4*)popg;
    float4 cA0 = p4[0], cA1 = p4[1], cA2 = p4[2], cA3 = p4[3];
    for (int c = 0; c < T; c += 16) {
        float4 cB0, cB1, cB2, cB3;
        if (c + 16 < T) {
            const float4* pn4 = p4 + (c + 16) / 4;
            cB0 = pn4[0]; cB1 = pn4[1]; cB2 = pn4[2]; cB3 = pn4[3];
        }
        step(cA0.x); step(cA0.y); step(cA0.z); step(cA0.w);
        step(cA1.x); step(cA1.y); step(cA1.z); step(cA1.w);
        step(cA2.x); step(cA2.y); step(cA2.z); step(cA2.w);
        step(cA3.x); step(cA3.y); step(cA3.z); step(cA3.w);
        if (c + 16 < T) { cA0 = cB0; cA1 = cB1; cA2 = cB2; cA3 = cB3; }
    }
}

// ---------------- K5: stack recurrence + readout ----------------------------
// Single-wave blocks: grid (D/16, B). Lane = 16 dsub x 4 ng (8 slots each).
// Coefficients recomputed from P: alpha = 1 - push*pp - pop*p, beta = push*pp,
// gamma = ZO*pop*p, w = pop*P[t+1] (pop factored out of the readout sum).
__launch_bounds__(64, 1)
__global__ void stack_kernel(const float* __restrict__ x,       // [B,T,D]
                             const float* __restrict__ Parr,    // [B,T,32]
                             const float* __restrict__ pop_arr, // [B,T]
                             float* __restrict__ out,           // [B,T,D]
                             int T) {
    const int b = blockIdx.y;
    const int dtile = blockIdx.x;              // 0..15
    const int lane = threadIdx.x;              // 0..63
    const int dsub = lane & 15;
    const int ng = lane >> 4;                  // slots ng*8..ng*8+7

    __shared__ float Ps[TTILE * 32];           // 4 KB
    __shared__ float xs[TTILE * 16];           // 2 KB
    __shared__ float ps[TTILE];                // 128 B

    const float* Pb = Parr + (size_t)b * T * 32;
    const float* xtb = x + (size_t)b * T * DDIM + dtile * 16;
    const float* popb = pop_arr + (size_t)b * T;
    float* ob = out + (size_t)b * T * DDIM + dtile * 16 + dsub;

    float4 Preg0, Preg1, Preg2, Preg3, xreg0, xreg1, popreg;
    const int f0 = lane, f1 = lane + 64;
    const int xr0 = f0 >> 2, xc0 = (f0 & 3) * 4;
    const int xr1 = f1 >> 2, xc1 = (f1 & 3) * 4;

    auto load_regs = [&](int t0) {
        const float4* P4 = (const float4*)(Pb + (size_t)t0 * 32);
        Preg0 = P4[lane];
        Preg1 = P4[lane + 64];
        Preg2 = P4[lane + 128];
        Preg3 = P4[lane + 192];
        xreg0 = *(const float4*)(xtb + (size_t)(t0 + xr0) * DDIM + xc0);
        xreg1 = *(const float4*)(xtb + (size_t)(t0 + xr1) * DDIM + xc1);
        if (lane < 8) popreg = *(const float4*)(popb + t0 + lane * 4);
    };
    auto store_lds = [&]() {
        ((float4*)Ps)[lane] = Preg0;
        ((float4*)Ps)[lane + 64] = Preg1;
        ((float4*)Ps)[lane + 128] = Preg2;
        ((float4*)Ps)[lane + 192] = Preg3;
        ((float4*)xs)[f0] = xreg0;
        ((float4*)xs)[f1] = xreg1;
        if (lane < 8) ((float4*)ps)[lane] = popreg;
    };

    float st[8], pc[8];
#pragma unroll
    for (int i = 0; i < 8; i++) { st[i] = ZO; pc[i] = ZO; }
    if (ng == 0) pc[0] = 1.0f;                 // P[0] one-hot at slot 0

    load_regs(0);
    store_lds();

    const int NT = T / TTILE;
    for (int tile = 0; tile < NT; tile++) {
        if (tile + 1 < NT) load_regs((tile + 1) * TTILE);   // global -> regs
        const int tg0 = tile * TTILE;
#pragma unroll 4
        for (int tl = 0; tl < TTILE; tl++) {
            const float pop = ps[tl];
            const float push = 1.0f - pop;
            const float4 pn0 = *(const float4*)(Ps + tl * 32 + ng * 8);
            const float4 pn1 = *(const float4*)(Ps + tl * 32 + ng * 8 + 4);
            const float xv = xs[tl * 16 + dsub];
            // slot ng*8-1 (wrap) = previous group's last element
            const float pm1 = __shfl(pc[7], ((ng + 3) & 3) * 16 + dsub, 64);
            const float pn[8] = {pn0.x, pn0.y, pn0.z, pn0.w,
                                 pn1.x, pn1.y, pn1.z, pn1.w};
            float acc = 0.f;
#pragma unroll
            for (int i = 0; i < 8; i++) {
                const float p_s = pc[i];
                const float pp_s = (i == 0) ? pm1 : pc[i - 1];
                const float t0v = pop * p_s;
                const float m = fmaf(push, pp_s, t0v);
                const float alpha = 1.0f - m;
                const float beta = push * pp_s;
                const float bxg = fmaf(beta, xv, ZO * t0v);
                const float ns = fmaf(alpha, st[i], bxg);
                st[i] = ns;
                acc = fmaf(pn[i], ns, acc);    // w = pop*pn, pop factored out
            }
#pragma unroll
            for (int i = 0; i < 8; i++) pc[i] = pn[i];
            acc += __shfl_xor(acc, 16, 64);
            acc += __shfl_xor(acc, 32, 64);
            if (ng == 0) ob[(size_t)(tg0 + tl) * DDIM] = pop * acc;
        }
        // per-wave DS ops are in-order: safe to overwrite after inner reads
        if (tile + 1 < NT) store_lds();
    }
}

// ---------------- Fallback: monolithic kernel (correct, slower) -------------
__launch_bounds__(256, 1)
__global__ void neuralstack_kernel(const float* __restrict__ x,
                                   const float* __restrict__ should_pop,
                                   const float* __restrict__ sharpen_ptr,
                                   const float* __restrict__ latch_enable,
                                   const float* __restrict__ latch_init,
                                   float* __restrict__ out,
                                   int T) {
    const int b = blockIdx.x;
    const int tid = threadIdx.x;
    const int wave = tid >> 6;
    const int lane = tid & 63;
    __shared__ float red[2][16];
    const float sp_d = should_pop[tid];
    const float le_d = latch_enable[tid];
    const float sharpen = sharpen_ptr[0];
    float latch = latch_init[(size_t)b * DDIM + tid];
    float a0 = sp_d * sp_d, a1 = le_d * le_d;
#pragma unroll
    for (int off = 32; off >= 1; off >>= 1) {
        a0 += __shfl_xor(a0, off, 64);
        a1 += __shfl_xor(a1, off, 64);
    }
    if (lane == 0) { red[0][wave * 4] = a0; red[0][wave * 4 + 1] = a1; }
    __syncthreads();
    const float an_sp = fmaxf(sqrtf(red[0][0] + red[0][4] + red[0][8] + red[0][12]), EPSC);
    const float an_le = fmaxf(sqrtf(red[0][1] + red[0][5] + red[0][9] + red[0][13]), EPSC);
    __syncthreads();
    float st[NSTK], ptr[NSTK];
#pragma unroll
    for (int n = 0; n < NSTK; n++) { st[n] = ZO; ptr[n] = (n == 0) ? 1.0f : ZO; }
    const float* xb = x + (size_t)b * T * DDIM + tid;
    float* ob = out + (size_t)b * T * DDIM + tid;
    const bool sharp5 = (sharpen == 5.0f);
    float inp = xb[0];
    for (int t = 0; t < T; t++) {
        const int tn = (t + 1 < T) ? (t + 1) : (T - 1);
        const float inp_next = xb[(size_t)tn * DDIM];
        float r0 = sp_d * latch, r1 = latch * latch, r2 = le_d * inp, r3 = inp * inp;
#pragma unroll
        for (int off = 32; off >= 1; off >>= 1) {
            r0 += __shfl_xor(r0, off, 64);
            r1 += __shfl_xor(r1, off, 64);
            r2 += __shfl_xor(r2, off, 64);
            r3 += __shfl_xor(r3, off, 64);
        }
        const int buf = t & 1;
        if (lane == 0) {
            red[buf][wave * 4] = r0; red[buf][wave * 4 + 1] = r1;
            red[buf][wave * 4 + 2] = r2; red[buf][wave * 4 + 3] = r3;
        }
        __syncthreads();
        const float s0 = red[buf][0] + red[buf][4] + red[buf][8] + red[buf][12];
        const float s1 = red[buf][1] + red[buf][5] + red[buf][9] + red[buf][13];
        const float s2 = red[buf][2] + red[buf][6] + red[buf][10] + red[buf][14];
        const float s3 = red[buf][3] + red[buf][7] + red[buf][11] + red[buf][15];
        const float pop = elu_f(s0 / (an_sp * fmaxf(sqrtf(s1), EPSC)));
        const float push = 1.0f - pop;
        const float g = elu_f(s2 / (an_le * fmaxf(sqrtf(s3), EPSC)));
        float q[NSTK];
#pragma unroll
        for (int n = 0; n < NSTK; n++) {
            const float pp = ptr[(n + NSTK - 1) & (NSTK - 1)];
            const float pn = ptr[(n + 1) & (NSTK - 1)];
            q[n] = fmaxf(push * pp + pop * pn, PEPS);
        }
        if (sharp5) {
#pragma unroll
            for (int n = 0; n < NSTK; n++) { const float v = q[n], v2 = v * v; q[n] = v2 * v2 * v; }
        } else {
#pragma unroll
            for (int n = 0; n < NSTK; n++) q[n] = exp2f(sharpen * log2f(q[n]));
        }
        float qa = 0.f, qb = 0.f, qc = 0.f, qd = 0.f;
#pragma unroll
        for (int n = 0; n < NSTK; n += 4) { qa += q[n]; qb += q[n+1]; qc += q[n+2]; qd += q[n+3]; }
        const float inv = 1.0f / fmaxf((qa + qb) + (qc + qd), EPSC);
        float sacc = 0.f;
#pragma unroll
        for (int n = 0; n < NSTK; n++) {
            const float pp = ptr[(n + NSTK - 1) & (NSTK - 1)];
            const float pc_ = ptr[n];
            const float ns = push * (st[n] + pp * (inp - st[n])) + pop * (st[n] + pc_ * (ZO - st[n]));
            st[n] = ns;
            sacc += ns * (q[n] * inv);
        }
#pragma unroll
        for (int n = 0; n < NSTK; n++) ptr[n] = q[n] * inv;
        ob[(size_t)t * DDIM] = pop * sacc;
        latch = fmaf(g, inp - latch, latch);
        inp = inp_next;
    }
}

extern "C" void kernel_launch(void* const* d_in, const int* in_sizes, int n_in,
                              void* d_out, int out_size, void* d_ws, size_t ws_size,
                              hipStream_t stream) {
    const float* x = (const float*)d_in[0];
    const float* should_pop = (const float*)d_in[1];
    const float* sharpen_ptr = (const float*)d_in[2];
    const float* latch_enable = (const float*)d_in[3];
    const float* latch_init = (const float*)d_in[4];
    float* out = (float*)d_out;

    const int D = in_sizes[1];                 // 256
    const int B = in_sizes[4] / D;             // 128
    const int T = in_sizes[0] / in_sizes[4];   // 256
    (void)n_in; (void)out_size;

    const size_t BT = (size_t)B * T;
    const size_t off_g = 0;
    const size_t off_pop = BT;
    const size_t off_L = 2 * BT;
    const size_t off_P = off_L + BT * D;
    const size_t need_floats = off_P + BT * 32;

    if (ws_size < need_floats * sizeof(float) || D != DDIM ||
        (T % TTILE) != 0 || (B % 2) != 0 || T > MAXT) {
        neuralstack_kernel<<<B, 256, 0, stream>>>(x, should_pop, sharpen_ptr,
                                                  latch_enable, latch_init, out, T);
        return;
    }

    float* ws = (float*)d_ws;
    float* g = ws + off_g;
    float* pop = ws + off_pop;
    float* L = ws + off_L;
    float* P = ws + off_P;

    gate4_kernel<<<dim3(T / 4, B), 256, 0, stream>>>(x, latch_enable, g, T);
    latch_scan_kernel<<<B * 4, 64, 0, stream>>>(x, latch_init, g, L, T);
    gate4_kernel<<<dim3(T / 4, B), 256, 0, stream>>>(L, should_pop, pop, T);
    ptr_scan_kernel<<<B / 2, 64, 0, stream>>>(pop, sharpen_ptr, P, T);
    stack_kernel<<<dim3(D / 16, B), 64, 0, stream>>>(x, P, pop, out, T);
}